// Round 13
// baseline (419.351 us; speedup 1.0000x reference)
//
#include <hip/hip_runtime.h>
#include <stdint.h>

// GRU-D forward, MI355X. B=512, steps S=128, T=128, H=256.
// R13: u_gemm wave-parallelism doubled: 256->512 thr/block (8 waves), 6 gate
// waves x 8 jt + 2 g-waves x 8 jt (was 3x16 + 1x16). 6 waves/SIMD occupancy
// (was 3), half the serial jt chain per wave. recur/prep_pack/bn_stats/fin
// identical to R12 (passed, 413.0us, absmax 0.0078).

#define NSTEP 128
#define NBAT  512

typedef __attribute__((ext_vector_type(8))) short bf16x8;
typedef __attribute__((ext_vector_type(4))) float f32x4;

__device__ __forceinline__ float bf2f(unsigned short u) {
  union { unsigned int i; float f; } v; v.i = ((unsigned int)u) << 16; return v.f;
}
__device__ __forceinline__ unsigned short f2bf(float f) {
  union { float f; unsigned int i; } v; v.f = f;
  unsigned int x = v.i;
  return (unsigned short)((x + 0x7fffu + ((x >> 16) & 1u)) >> 16);  // RNE
}
__device__ __forceinline__ unsigned int cvt_pk_bf16(float lo, float hi) {
  unsigned int r;
  asm("v_cvt_pk_bf16_f32 %0, %1, %2" : "=v"(r) : "v"(lo), "v"(hi));
  return r;
}
__device__ __forceinline__ unsigned short us4_get(ushort4 v, int r) {
  return r == 0 ? v.x : r == 1 ? v.y : r == 2 ? v.z : v.w;
}
#define PINV(x) asm volatile("" : "+v"(x))
// block barrier WITHOUT vmcnt drain (global loads stay in flight).
#define BSYNC() do { asm volatile("s_waitcnt lgkmcnt(0)" ::: "memory"); \
                     __builtin_amdgcn_s_barrier(); } while (0)

#define L2E  1.44269504088896f
#define L2E2 2.88539008177793f

// ---------------------------------------------------------------------------
// prep_pack: blocks [0,1024) = prep (imputation + Cin build); blocks
// [1024, 1024+4616) = weight packing. 128 threads/block.
// ---------------------------------------------------------------------------
__global__ __launch_bounds__(128) void prep_pack(
    const float* __restrict__ X, const float* __restrict__ Xmean,
    const float* __restrict__ Wgx, const float* __restrict__ bgx,
    const float* __restrict__ Wz, const float* __restrict__ Wr,
    const float* __restrict__ Wh, const float* __restrict__ Wgh,
    const float* __restrict__ bz, const float* __restrict__ br,
    const float* __restrict__ bh, const float* __restrict__ bgh,
    unsigned short* __restrict__ Cin, unsigned short* __restrict__ Wpre,
    unsigned short* __restrict__ Wzrh, unsigned short* __restrict__ WhhP,
    float* __restrict__ Bpre) {
  if (blockIdx.x >= 1024) {  // ---- weight packing ----
    int id = (blockIdx.x - 1024) * 128 + threadIdx.x;  // 0 .. 590847
    if (id < 1024 * 384) {
      int j = id / 384, k = id % 384;
      float v = 0.f;
      if (j < 768) {
        const float* W = (j < 256) ? Wz : (j < 512) ? Wr : Wh;
        int jj = j & 255;
        if (k < 128)      v = W[jj * 512 + k];
        else if (k < 256) v = W[jj * 512 + 384 + (k - 128)];
        v *= (j < 512) ? L2E : L2E2;
      } else {
        int jj = j - 768;
        if (k >= 256) v = Wgh[jj * 128 + (k - 256)];  // g rows unscaled
      }
      Wpre[id] = f2bf(v);
      return;
    }
    int id2 = id - 1024 * 384;
    if (id2 < 512 * 256) {
      int j = id2 >> 8, i = id2 & 255;
      float v = (j < 256) ? Wz[j * 512 + 128 + i] : Wr[(j - 256) * 512 + 128 + i];
      Wzrh[id2] = f2bf(v * L2E);
      return;
    }
    int id3 = id2 - 512 * 256;
    if (id3 < 256 * 256) {
      int j = id3 >> 8, i = id3 & 255;
      WhhP[id3] = f2bf(Wh[j * 512 + 128 + i] * L2E2);
      return;
    }
    int id4 = id3 - 256 * 256;
    if (id4 < 1024) {
      float v = (id4 < 256) ? bz[id4] * L2E : (id4 < 512) ? br[id4 - 256] * L2E
              : (id4 < 768) ? bh[id4 - 512] * L2E2 : bgh[id4 - 768];
      Bpre[id4] = v;
    }
    return;
  }
  // ---- prep: imputation + Cin[s][b][k] (k: 0:128 x~, 128:256 m, 256:384 d) ----
  __shared__ unsigned short lx[64][132], lm[64][132], ldl[64][132];
  int b = blockIdx.x >> 1, tc = blockIdx.x & 1;
  int s = threadIdx.x;
  const float* Xb = X + (size_t)b * 384 * 128;
  for (int tt = 0; tt < 64; ++tt) {
    int t = tc * 64 + tt;
    float m = Xb[(3 * t + 0) * 128 + s];
    float x = Xb[(3 * t + 1) * 128 + s];
    float d = Xb[(3 * t + 2) * 128 + s];
    float wg = Wgx[t * 128 + t];
    float bg = bgx[t];
    float dx = __expf(-fmaxf(d * wg + bg, 0.f));
    float xm = Xmean[s * 128 + t];   // X_mean[0][s][t], L2-resident
    float xt = m * x + (1.f - m) * (dx * x + (1.f - dx) * xm);
    lx[tt][s]  = f2bf(xt);
    lm[tt][s]  = f2bf(m);
    ldl[tt][s] = f2bf(d);
  }
  __syncthreads();
  for (int s0 = 0; s0 < 128; s0 += 2) {
    int ss = s0 + (threadIdx.x >> 6);
    int t  = threadIdx.x & 63;
    size_t base = ((size_t)ss * NBAT + b) * 384;
    Cin[base +       tc * 64 + t] = lx[t][ss];
    Cin[base + 128 + tc * 64 + t] = lm[t][ss];
    Cin[base + 256 + tc * 64 + t] = ldl[t][ss];
  }
}

// ---------------------------------------------------------------------------
// u_gemm: Upre[s][bt][b16][1024 j] bf16 = Cin @ Wpre^T + Bpre (batch-major).
// 512 thr / 8 waves: wid<6 = gate rows (128 j each, K 0:256); wid 6-7 =
// g rows -> DH = exp(-relu(preact)) (128 j each, K 256:384).
// ---------------------------------------------------------------------------
__global__ __launch_bounds__(512) void u_gemm(const unsigned short* __restrict__ Cin,
                                              const unsigned short* __restrict__ Wpre,
                                              const float* __restrict__ Bpre,
                                              unsigned short* __restrict__ Upre) {
  __shared__ unsigned short Ash[64][392];
  int s  = blockIdx.x >> 3;
  int bc = blockIdx.x & 7;
  int b0 = bc * 64;
  {
    int r = threadIdx.x >> 3, part = threadIdx.x & 7;   // 64 rows x 8 parts
    const uint4* src = (const uint4*)(Cin + ((size_t)s * NBAT + b0 + r) * 384);
    uint4* dst = (uint4*)&Ash[r][0];
#pragma unroll
    for (int q = 0; q < 6; ++q) dst[part + q * 8] = src[part + q * 8];  // 48 uint4
  }
  __syncthreads();
  int wid = threadIdx.x >> 6, lane = threadIdx.x & 63;
  int col = lane & 15, kq = lane >> 4;

  if (wid < 6) {  // gate rows (z,r,h), K = 0:256, 128 j-rows per wave
    int jbase = wid * 128;
    bf16x8 af[4][8];
#pragma unroll
    for (int mt = 0; mt < 4; ++mt)
#pragma unroll
      for (int kt = 0; kt < 8; ++kt)
        af[mt][kt] = *(const bf16x8*)&Ash[mt * 16 + col][kt * 32 + kq * 8];
#pragma unroll 2
    for (int jt = 0; jt < 8; ++jt) {
      int j0 = jbase + jt * 16;
      const unsigned short* wrow = Wpre + (size_t)(j0 + col) * 384 + kq * 8;
      f32x4 C[4] = {{0,0,0,0},{0,0,0,0},{0,0,0,0},{0,0,0,0}};
#pragma unroll
      for (int kt = 0; kt < 8; ++kt) {
        bf16x8 bw = *(const bf16x8*)(wrow + kt * 32);
        C[0] = __builtin_amdgcn_mfma_f32_16x16x32_bf16(bw, af[0][kt], C[0], 0, 0, 0);
        C[1] = __builtin_amdgcn_mfma_f32_16x16x32_bf16(bw, af[1][kt], C[1], 0, 0, 0);
        C[2] = __builtin_amdgcn_mfma_f32_16x16x32_bf16(bw, af[2][kt], C[2], 0, 0, 0);
        C[3] = __builtin_amdgcn_mfma_f32_16x16x32_bf16(bw, af[3][kt], C[3], 0, 0, 0);
      }
      int jv = j0 + kq * 4;
      float4 bias = *(const float4*)&Bpre[jv];
#pragma unroll
      for (int mt = 0; mt < 4; ++mt) {
        int bt = bc * 4 + mt;
        ushort4 o;
        o.x = f2bf(C[mt][0] + bias.x); o.y = f2bf(C[mt][1] + bias.y);
        o.z = f2bf(C[mt][2] + bias.z); o.w = f2bf(C[mt][3] + bias.w);
        *(ushort4*)(Upre + (((size_t)s * 32 + bt) * 16 + col) * 1024 + jv) = o;
      }
    }
  } else {  // g rows -> DH = exp(-relu(preact)), K = 256:384, 128 j per wave
    bf16x8 af[4][4];
#pragma unroll
    for (int mt = 0; mt < 4; ++mt)
#pragma unroll
      for (int kt = 0; kt < 4; ++kt)
        af[mt][kt] = *(const bf16x8*)&Ash[mt * 16 + col][256 + kt * 32 + kq * 8];
#pragma unroll 2
    for (int jt = 0; jt < 8; ++jt) {
      int j0 = 768 + (wid - 6) * 128 + jt * 16;
      const unsigned short* wrow = Wpre + (size_t)(j0 + col) * 384 + 256 + kq * 8;
      f32x4 C[4] = {{0,0,0,0},{0,0,0,0},{0,0,0,0},{0,0,0,0}};
#pragma unroll
      for (int kt = 0; kt < 4; ++kt) {
        bf16x8 bw = *(const bf16x8*)(wrow + kt * 32);
        C[0] = __builtin_amdgcn_mfma_f32_16x16x32_bf16(bw, af[0][kt], C[0], 0, 0, 0);
        C[1] = __builtin_amdgcn_mfma_f32_16x16x32_bf16(bw, af[1][kt], C[1], 0, 0, 0);
        C[2] = __builtin_amdgcn_mfma_f32_16x16x32_bf16(bw, af[2][kt], C[2], 0, 0, 0);
        C[3] = __builtin_amdgcn_mfma_f32_16x16x32_bf16(bw, af[3][kt], C[3], 0, 0, 0);
      }
      int jv = j0 + kq * 4;
      float4 bias = *(const float4*)&Bpre[jv];
#pragma unroll
      for (int mt = 0; mt < 4; ++mt) {
        int bt = bc * 4 + mt;
        ushort4 o;
        o.x = f2bf(__expf(-fmaxf(C[mt][0] + bias.x, 0.f)));
        o.y = f2bf(__expf(-fmaxf(C[mt][1] + bias.y, 0.f)));
        o.z = f2bf(__expf(-fmaxf(C[mt][2] + bias.z, 0.f)));
        o.w = f2bf(__expf(-fmaxf(C[mt][3] + bias.w, 0.f)));
        *(ushort4*)(Upre + (((size_t)s * 32 + bt) * 16 + col) * 1024 + jv) = o;
      }
    }
  }
}

// ---------------------------------------------------------------------------
// recur: 32 persistent blocks x 512 thr (8 waves), 16 batch rows/block.
// R8 structure: Wz/Wr reg-resident, Whh in swizzled LDS, Ub prefetched
// across raw barriers, exp2-native activations, zero-VALU LDS addressing.
// ---------------------------------------------------------------------------
__global__ __launch_bounds__(512, 2) void recur(const unsigned short* __restrict__ Upre,
                                                const unsigned short* __restrict__ Wzrh,
                                                const unsigned short* __restrict__ WhhP,
                                                float* __restrict__ hT) {
  __shared__ unsigned short hb[16 * 256];   // decayed h bf16, 512B rows, swizzled
  __shared__ unsigned short qb[16 * 256];   // q = sig(r)*h bf16, swizzled
  __shared__ unsigned short WhL[65536];     // Whh, XOR-swizzled rows (131072 B)
  int bt = blockIdx.x, tid = threadIdx.x;
  int wid = tid >> 6, lane = tid & 63, col = lane & 15, kq = lane >> 4;
  const int hsw = (col & 7) << 4;

  // stage Whh -> LDS, swizzle byte ^= (row&7)<<4; 32 16B-chunks per 512B row.
#pragma unroll
  for (int i = 0; i < 16; ++i) {
    int f = tid + i * 512;
    int row = f >> 5, c = f & 31;
    bf16x8 v = *(const bf16x8*)(WhhP + (size_t)f * 8);
    *(bf16x8*)((char*)WhL + row * 512 + ((c * 16) ^ ((row & 7) << 4))) = v;
  }
  for (int i = tid; i < 16 * 256; i += 512) hb[i] = 0;

  // persistent z/r weight fragments (A-operand layout)
  bf16x8 wzf[2][8], wrf[2][8];
#pragma unroll
  for (int mt = 0; mt < 2; ++mt)
#pragma unroll
    for (int kt = 0; kt < 8; ++kt) {
      int j = wid * 32 + mt * 16 + col;
      wzf[mt][kt] = *(const bf16x8*)(Wzrh + (size_t)j * 256 + kt * 32 + kq * 8);
      wrf[mt][kt] = *(const bf16x8*)(Wzrh + (size_t)(256 + j) * 256 + kt * 32 + kq * 8);
      PINV(wzf[mt][kt]);
      PINV(wrf[mt][kt]);
    }

  const int joff0 = wid * 32 + kq * 4;
  // zero-VALU swizzled addressing (bit-6 / bits<6 exact split of the XOR)
  const int hs_lo = hsw & 48, hs_hi = hsw & 64;
  const int cq  = (kq * 16) ^ hs_lo;
  const int rbA = col * 512 + cq + hs_hi;           // even kt
  const int rbB = col * 512 + cq - hs_hi;           // odd kt
  const int row0 = wid * 32 + col;                  // (row0&7)==(col&7)
  const int wrbA = row0 * 512 + cq + hs_hi;
  const int wrbB = row0 * 512 + cq - hs_hi;
  const int wby0 = col * 512 + ((joff0 * 2) ^ hsw);        // write byte, mt=0
  const int wby1 = col * 512 + (((joff0 + 16) * 2) ^ hsw); // write byte, mt=1

  const unsigned short* Ub0 = Upre + ((size_t)bt * 16 + col) * 1024;
  const size_t SS = 32 * 16 * 1024;  // per-step stride (shorts)

  ushort4 uz[2], ur[2], uh[2], ug[2];
#pragma unroll
  for (int mt = 0; mt < 2; ++mt) {
    uz[mt] = *(const ushort4*)(Ub0 + 0   + joff0 + mt * 16);
    ur[mt] = *(const ushort4*)(Ub0 + 256 + joff0 + mt * 16);
    uh[mt] = *(const ushort4*)(Ub0 + 512 + joff0 + mt * 16);
    ug[mt] = *(const ushort4*)(Ub0 + SS + 768 + joff0 + mt * 16);  // DH, step 1
  }
  const unsigned short* pnext = Ub0 + SS + joff0;       // step s+1 base
  const unsigned short* pg    = Ub0 + 2 * SS + 768 + joff0;  // DH, step s+2
  f32x4 Hst[2] = {{0,0,0,0},{0,0,0,0}};
  float zk[2][4];
  BSYNC();

  for (int s = 0; s < NSTEP; ++s) {
    // ---- GEMM1: z and r (4 independent accumulation chains) ----
    f32x4 Cz[2] = {{0,0,0,0},{0,0,0,0}}, Cr[2] = {{0,0,0,0},{0,0,0,0}};
#pragma unroll
    for (int kt = 0; kt < 8; ++kt) {
      bf16x8 b = *(const bf16x8*)((const char*)hb + ((kt & 1) ? rbB : rbA) + kt * 64);
      Cz[0] = __builtin_amdgcn_mfma_f32_16x16x32_bf16(wzf[0][kt], b, Cz[0], 0, 0, 0);
      Cr[0] = __builtin_amdgcn_mfma_f32_16x16x32_bf16(wrf[0][kt], b, Cr[0], 0, 0, 0);
      Cz[1] = __builtin_amdgcn_mfma_f32_16x16x32_bf16(wzf[1][kt], b, Cz[1], 0, 0, 0);
      Cr[1] = __builtin_amdgcn_mfma_f32_16x16x32_bf16(wrf[1][kt], b, Cr[1], 0, 0, 0);
    }
    // epilogue: z kept in regs, q -> LDS via cvt_pk (exp2-native sigmoids)
#pragma unroll
    for (int mt = 0; mt < 2; ++mt) {
      float qv[4];
#pragma unroll
      for (int r = 0; r < 4; ++r) {
        float xz = Cz[mt][r] + bf2f(us4_get(uz[mt], r));
        float xr = Cr[mt][r] + bf2f(us4_get(ur[mt], r));
        float zv = __builtin_amdgcn_rcpf(1.f + __builtin_amdgcn_exp2f(-xz));
        float rv = __builtin_amdgcn_rcpf(1.f + __builtin_amdgcn_exp2f(-xr));
        zk[mt][r] = zv;
        qv[r] = rv * Hst[mt][r];
      }
      uint2 qw;
      qw.x = cvt_pk_bf16(qv[0], qv[1]);
      qw.y = cvt_pk_bf16(qv[2], qv[3]);
      *(uint2*)((char*)qb + (mt ? wby1 : wby0)) = qw;
    }
    // prefetch uz/ur for s+1 (in flight across the raw barrier)
#pragma unroll
    for (int mt = 0; mt < 2; ++mt) {
      uz[mt] = *(const ushort4*)(pnext + 0   + mt * 16);
      ur[mt] = *(const ushort4*)(pnext + 256 + mt * 16);
    }
    BSYNC();
    // ---- GEMM2: ht (Whh from swizzled LDS, imm-offset reads) ----
    f32x4 Ch[2] = {{0,0,0,0},{0,0,0,0}};
#pragma unroll
    for (int kt = 0; kt < 8; ++kt) {
      int ro = ((kt & 1) ? rbB : rbA) + kt * 64;
      int wo = ((kt & 1) ? wrbB : wrbA) + kt * 64;
      bf16x8 b  = *(const bf16x8*)((const char*)qb + ro);
      bf16x8 w0 = *(const bf16x8*)((const char*)WhL + wo);
      bf16x8 w1 = *(const bf16x8*)((const char*)WhL + wo + 16 * 512);
      Ch[0] = __builtin_amdgcn_mfma_f32_16x16x32_bf16(w0, b, Ch[0], 0, 0, 0);
      Ch[1] = __builtin_amdgcn_mfma_f32_16x16x32_bf16(w1, b, Ch[1], 0, 0, 0);
    }
    // epilogue: ht (exp2-native tanh), state update, decay via precomputed DH
#pragma unroll
    for (int mt = 0; mt < 2; ++mt) {
      float hn[4];
#pragma unroll
      for (int r = 0; r < 4; ++r) {
        float p = Ch[mt][r] + bf2f(us4_get(uh[mt], r));   // already 2log2e-scaled
        float e = __builtin_amdgcn_exp2f(p);
        float rr = __builtin_amdgcn_rcpf(e + 1.f);
        float th = fmaf(-2.f, rr, 1.f);
        float H = Hst[mt][r];
        hn[r] = fmaf(zk[mt][r], th - H, H);
      }
      if (s < NSTEP - 1) {
        float Hn[4];
#pragma unroll
        for (int r = 0; r < 4; ++r) {
          Hn[r] = hn[r] * bf2f(us4_get(ug[mt], r));  // ug holds DH already
          Hst[mt][r] = Hn[r];
        }
        uint2 hw;
        hw.x = cvt_pk_bf16(Hn[0], Hn[1]);
        hw.y = cvt_pk_bf16(Hn[2], Hn[3]);
        *(uint2*)((char*)hb + (mt ? wby1 : wby0)) = hw;
      } else {
        float4 o4; o4.x = hn[0]; o4.y = hn[1]; o4.z = hn[2]; o4.w = hn[3];
        *(float4*)&hT[((size_t)bt * 16 + col) * 256 + joff0 + mt * 16] = o4;
      }
    }
    // prefetch uh for s+1, DH for s+2 (overshoot in-bounds, unused)
#pragma unroll
    for (int mt = 0; mt < 2; ++mt) {
      uh[mt] = *(const ushort4*)(pnext + 512 + mt * 16);
      ug[mt] = *(const ushort4*)(pg + mt * 16);
    }
    pnext += SS;
    pg += SS;
    BSYNC();
  }
}

// ---------------------------------------------------------------------------
// bn_stats: one block per feature j; 64 lanes reduce over batch.
// av[j] = scale; av[256+j] = per-feature bias term (no atomics).
// ---------------------------------------------------------------------------
__global__ __launch_bounds__(64) void bn_stats(const float* __restrict__ hT,
                                               const float* __restrict__ gamma,
                                               const float* __restrict__ beta,
                                               const float* __restrict__ Wfc,
                                               const float* __restrict__ bfc,
                                               float* __restrict__ av) {
  int j = blockIdx.x, lane = threadIdx.x;
  float sum = 0.f, sum2 = 0.f;
#pragma unroll
  for (int b = lane; b < NBAT; b += 64) {
    float v = hT[(size_t)b * 256 + j];
    sum += v; sum2 += v * v;
  }
  for (int o = 32; o; o >>= 1) {
    sum  += __shfl_down(sum, o);
    sum2 += __shfl_down(sum2, o);
  }
  if (lane == 0) {
    float mu = sum * (1.f / NBAT);
    float var = sum2 * (1.f / NBAT) - mu * mu;
    float a = gamma[j] * Wfc[j] * rsqrtf(var + 1e-5f);
    av[j] = a;
    av[256 + j] = beta[j] * Wfc[j] - a * mu + (j == 0 ? bfc[0] : 0.f);
  }
}

__global__ __launch_bounds__(64) void fin(const float* __restrict__ hT,
                                          const float* __restrict__ av,
                                          float* __restrict__ out) {
  int b = blockIdx.x, lane = threadIdx.x;
  float4 hv = *(const float4*)&hT[(size_t)b * 256 + lane * 4];
  float4 a  = *(const float4*)&av[lane * 4];
  float4 c  = *(const float4*)&av[256 + lane * 4];
  float d = hv.x * a.x + hv.y * a.y + hv.z * a.z + hv.w * a.w
          + c.x + c.y + c.z + c.w;   // reduce sums all 256 bias terms once
  for (int o = 32; o; o >>= 1) d += __shfl_down(d, o);
  if (lane == 0) out[b] = d;
}

extern "C" void kernel_launch(void* const* d_in, const int* in_sizes, int n_in,
                              void* d_out, int out_size, void* d_ws, size_t ws_size,
                              hipStream_t stream) {
  (void)in_sizes; (void)n_in; (void)out_size; (void)ws_size;
  const float* X     = (const float*)d_in[0];
  const float* Xmean = (const float*)d_in[1];
  const float* Wz    = (const float*)d_in[2];
  const float* bz    = (const float*)d_in[3];
  const float* Wr    = (const float*)d_in[4];
  const float* br    = (const float*)d_in[5];
  const float* Wh    = (const float*)d_in[6];
  const float* bh    = (const float*)d_in[7];
  const float* Wgx   = (const float*)d_in[8];
  const float* bgx   = (const float*)d_in[9];
  const float* Wgh   = (const float*)d_in[10];
  const float* bgh   = (const float*)d_in[11];
  const float* gamma = (const float*)d_in[12];
  const float* beta  = (const float*)d_in[13];
  const float* Wfc   = (const float*)d_in[14];
  const float* bfc   = (const float*)d_in[15];
  float* out = (float*)d_out;
  char* ws = (char*)d_ws;

  unsigned short* Upre = (unsigned short*)(ws + 0ull);           // 134217728 B
  unsigned short* Cin  = (unsigned short*)(ws + 134217728ull);   // 50331648 B
  unsigned short* Wpre = (unsigned short*)(ws + 184549376ull);   // 786432 B
  unsigned short* Wzrh = (unsigned short*)(ws + 185335808ull);   // 262144 B
  unsigned short* WhhP = (unsigned short*)(ws + 185597952ull);   // 131072 B
  float*          Bpre = (float*)(ws + 185729024ull);            // 4096 B
  float*          hT   = (float*)(ws + 185733120ull);            // 524288 B
  float*          av   = (float*)(ws + 186257408ull);            // 2048 B (512 f)

  prep_pack<<<1024 + 4616, 128, 0, stream>>>(X, Xmean, Wgx, bgx,
                                             Wz, Wr, Wh, Wgh, bz, br, bh, bgh,
                                             Cin, Wpre, Wzrh, WhhP, Bpre);
  u_gemm<<<1024, 512, 0, stream>>>(Cin, Wpre, Bpre, Upre);
  recur<<<32, 512, 0, stream>>>(Upre, Wzrh, WhhP, hT);
  bn_stats<<<256, 64, 0, stream>>>(hT, gamma, beta, Wfc, bfc, av);
  fin<<<512, 64, 0, stream>>>(hT, av, out);
}

// Round 14
// 412.294 us; speedup vs baseline: 1.0171x; 1.0171x over previous
//
#include <hip/hip_runtime.h>
#include <stdint.h>

// GRU-D forward, MI355X. B=512, steps S=128, T=128, H=256.
// R14: exact revert to R12 (best: 413.0us, absmax 0.0078) — R13's u_gemm
// 512-thr variant regressed (419.4us; 8-wave blocks -> 2 blocks/CU, same
// waves/SIMD, worse A-frag amortization). This is the final configuration:
// recur at structural floor (269.5us), tail HBM/launch-bound.

#define NSTEP 128
#define NBAT  512

typedef __attribute__((ext_vector_type(8))) short bf16x8;
typedef __attribute__((ext_vector_type(4))) float f32x4;

__device__ __forceinline__ float bf2f(unsigned short u) {
  union { unsigned int i; float f; } v; v.i = ((unsigned int)u) << 16; return v.f;
}
__device__ __forceinline__ unsigned short f2bf(float f) {
  union { float f; unsigned int i; } v; v.f = f;
  unsigned int x = v.i;
  return (unsigned short)((x + 0x7fffu + ((x >> 16) & 1u)) >> 16);  // RNE
}
__device__ __forceinline__ unsigned int cvt_pk_bf16(float lo, float hi) {
  unsigned int r;
  asm("v_cvt_pk_bf16_f32 %0, %1, %2" : "=v"(r) : "v"(lo), "v"(hi));
  return r;
}
__device__ __forceinline__ unsigned short us4_get(ushort4 v, int r) {
  return r == 0 ? v.x : r == 1 ? v.y : r == 2 ? v.z : v.w;
}
#define PINV(x) asm volatile("" : "+v"(x))
// block barrier WITHOUT vmcnt drain (global loads stay in flight).
#define BSYNC() do { asm volatile("s_waitcnt lgkmcnt(0)" ::: "memory"); \
                     __builtin_amdgcn_s_barrier(); } while (0)

#define L2E  1.44269504088896f
#define L2E2 2.88539008177793f

// ---------------------------------------------------------------------------
// prep_pack: blocks [0,1024) = prep (imputation + Cin build); blocks
// [1024, 1024+4616) = weight packing. 128 threads/block.
// ---------------------------------------------------------------------------
__global__ __launch_bounds__(128) void prep_pack(
    const float* __restrict__ X, const float* __restrict__ Xmean,
    const float* __restrict__ Wgx, const float* __restrict__ bgx,
    const float* __restrict__ Wz, const float* __restrict__ Wr,
    const float* __restrict__ Wh, const float* __restrict__ Wgh,
    const float* __restrict__ bz, const float* __restrict__ br,
    const float* __restrict__ bh, const float* __restrict__ bgh,
    unsigned short* __restrict__ Cin, unsigned short* __restrict__ Wpre,
    unsigned short* __restrict__ Wzrh, unsigned short* __restrict__ WhhP,
    float* __restrict__ Bpre) {
  if (blockIdx.x >= 1024) {  // ---- weight packing ----
    int id = (blockIdx.x - 1024) * 128 + threadIdx.x;  // 0 .. 590847
    if (id < 1024 * 384) {
      int j = id / 384, k = id % 384;
      float v = 0.f;
      if (j < 768) {
        const float* W = (j < 256) ? Wz : (j < 512) ? Wr : Wh;
        int jj = j & 255;
        if (k < 128)      v = W[jj * 512 + k];
        else if (k < 256) v = W[jj * 512 + 384 + (k - 128)];
        v *= (j < 512) ? L2E : L2E2;
      } else {
        int jj = j - 768;
        if (k >= 256) v = Wgh[jj * 128 + (k - 256)];  // g rows unscaled
      }
      Wpre[id] = f2bf(v);
      return;
    }
    int id2 = id - 1024 * 384;
    if (id2 < 512 * 256) {
      int j = id2 >> 8, i = id2 & 255;
      float v = (j < 256) ? Wz[j * 512 + 128 + i] : Wr[(j - 256) * 512 + 128 + i];
      Wzrh[id2] = f2bf(v * L2E);
      return;
    }
    int id3 = id2 - 512 * 256;
    if (id3 < 256 * 256) {
      int j = id3 >> 8, i = id3 & 255;
      WhhP[id3] = f2bf(Wh[j * 512 + 128 + i] * L2E2);
      return;
    }
    int id4 = id3 - 256 * 256;
    if (id4 < 1024) {
      float v = (id4 < 256) ? bz[id4] * L2E : (id4 < 512) ? br[id4 - 256] * L2E
              : (id4 < 768) ? bh[id4 - 512] * L2E2 : bgh[id4 - 768];
      Bpre[id4] = v;
    }
    return;
  }
  // ---- prep: imputation + Cin[s][b][k] (k: 0:128 x~, 128:256 m, 256:384 d) ----
  __shared__ unsigned short lx[64][132], lm[64][132], ldl[64][132];
  int b = blockIdx.x >> 1, tc = blockIdx.x & 1;
  int s = threadIdx.x;
  const float* Xb = X + (size_t)b * 384 * 128;
  for (int tt = 0; tt < 64; ++tt) {
    int t = tc * 64 + tt;
    float m = Xb[(3 * t + 0) * 128 + s];
    float x = Xb[(3 * t + 1) * 128 + s];
    float d = Xb[(3 * t + 2) * 128 + s];
    float wg = Wgx[t * 128 + t];
    float bg = bgx[t];
    float dx = __expf(-fmaxf(d * wg + bg, 0.f));
    float xm = Xmean[s * 128 + t];   // X_mean[0][s][t], L2-resident
    float xt = m * x + (1.f - m) * (dx * x + (1.f - dx) * xm);
    lx[tt][s]  = f2bf(xt);
    lm[tt][s]  = f2bf(m);
    ldl[tt][s] = f2bf(d);
  }
  __syncthreads();
  for (int s0 = 0; s0 < 128; s0 += 2) {
    int ss = s0 + (threadIdx.x >> 6);
    int t  = threadIdx.x & 63;
    size_t base = ((size_t)ss * NBAT + b) * 384;
    Cin[base +       tc * 64 + t] = lx[t][ss];
    Cin[base + 128 + tc * 64 + t] = lm[t][ss];
    Cin[base + 256 + tc * 64 + t] = ldl[t][ss];
  }
}

// ---------------------------------------------------------------------------
// u_gemm: Upre[s][bt][b16][1024 j] bf16 = Cin @ Wpre^T + Bpre (batch-major).
// g-section (j 768:1024) stores DH = exp(-relu(preact)) directly.
// ---------------------------------------------------------------------------
__global__ __launch_bounds__(256) void u_gemm(const unsigned short* __restrict__ Cin,
                                              const unsigned short* __restrict__ Wpre,
                                              const float* __restrict__ Bpre,
                                              unsigned short* __restrict__ Upre) {
  __shared__ unsigned short Ash[64][392];
  int s  = blockIdx.x >> 3;
  int bc = blockIdx.x & 7;
  int b0 = bc * 64;
  {
    int r = threadIdx.x >> 2, part = threadIdx.x & 3;
    const uint4* src = (const uint4*)(Cin + ((size_t)s * NBAT + b0 + r) * 384);
    uint4* dst = (uint4*)&Ash[r][0];
#pragma unroll
    for (int q = 0; q < 12; ++q) dst[part + q * 4] = src[part + q * 4];
  }
  __syncthreads();
  int wid = threadIdx.x >> 6, lane = threadIdx.x & 63;
  int col = lane & 15, kq = lane >> 4;

  if (wid < 3) {  // gate rows (z,r,h), K = 0:256
    int jbase = wid * 256;
    bf16x8 af[4][8];
#pragma unroll
    for (int mt = 0; mt < 4; ++mt)
#pragma unroll
      for (int kt = 0; kt < 8; ++kt)
        af[mt][kt] = *(const bf16x8*)&Ash[mt * 16 + col][kt * 32 + kq * 8];
#pragma unroll 2
    for (int jt = 0; jt < 16; ++jt) {
      int j0 = jbase + jt * 16;
      const unsigned short* wrow = Wpre + (size_t)(j0 + col) * 384 + kq * 8;
      f32x4 C[4] = {{0,0,0,0},{0,0,0,0},{0,0,0,0},{0,0,0,0}};
#pragma unroll
      for (int kt = 0; kt < 8; ++kt) {
        bf16x8 bw = *(const bf16x8*)(wrow + kt * 32);
        C[0] = __builtin_amdgcn_mfma_f32_16x16x32_bf16(bw, af[0][kt], C[0], 0, 0, 0);
        C[1] = __builtin_amdgcn_mfma_f32_16x16x32_bf16(bw, af[1][kt], C[1], 0, 0, 0);
        C[2] = __builtin_amdgcn_mfma_f32_16x16x32_bf16(bw, af[2][kt], C[2], 0, 0, 0);
        C[3] = __builtin_amdgcn_mfma_f32_16x16x32_bf16(bw, af[3][kt], C[3], 0, 0, 0);
      }
      int jv = j0 + kq * 4;
      float4 bias = *(const float4*)&Bpre[jv];
#pragma unroll
      for (int mt = 0; mt < 4; ++mt) {
        int bt = bc * 4 + mt;
        ushort4 o;
        o.x = f2bf(C[mt][0] + bias.x); o.y = f2bf(C[mt][1] + bias.y);
        o.z = f2bf(C[mt][2] + bias.z); o.w = f2bf(C[mt][3] + bias.w);
        *(ushort4*)(Upre + (((size_t)s * 32 + bt) * 16 + col) * 1024 + jv) = o;
      }
    }
  } else {  // g rows -> store DH = exp(-relu(preact)), K = 256:384
    bf16x8 af[4][4];
#pragma unroll
    for (int mt = 0; mt < 4; ++mt)
#pragma unroll
      for (int kt = 0; kt < 4; ++kt)
        af[mt][kt] = *(const bf16x8*)&Ash[mt * 16 + col][256 + kt * 32 + kq * 8];
#pragma unroll 2
    for (int jt = 0; jt < 16; ++jt) {
      int j0 = 768 + jt * 16;
      const unsigned short* wrow = Wpre + (size_t)(j0 + col) * 384 + 256 + kq * 8;
      f32x4 C[4] = {{0,0,0,0},{0,0,0,0},{0,0,0,0},{0,0,0,0}};
#pragma unroll
      for (int kt = 0; kt < 4; ++kt) {
        bf16x8 bw = *(const bf16x8*)(wrow + kt * 32);
        C[0] = __builtin_amdgcn_mfma_f32_16x16x32_bf16(bw, af[0][kt], C[0], 0, 0, 0);
        C[1] = __builtin_amdgcn_mfma_f32_16x16x32_bf16(bw, af[1][kt], C[1], 0, 0, 0);
        C[2] = __builtin_amdgcn_mfma_f32_16x16x32_bf16(bw, af[2][kt], C[2], 0, 0, 0);
        C[3] = __builtin_amdgcn_mfma_f32_16x16x32_bf16(bw, af[3][kt], C[3], 0, 0, 0);
      }
      int jv = j0 + kq * 4;
      float4 bias = *(const float4*)&Bpre[jv];
#pragma unroll
      for (int mt = 0; mt < 4; ++mt) {
        int bt = bc * 4 + mt;
        ushort4 o;
        o.x = f2bf(__expf(-fmaxf(C[mt][0] + bias.x, 0.f)));
        o.y = f2bf(__expf(-fmaxf(C[mt][1] + bias.y, 0.f)));
        o.z = f2bf(__expf(-fmaxf(C[mt][2] + bias.z, 0.f)));
        o.w = f2bf(__expf(-fmaxf(C[mt][3] + bias.w, 0.f)));
        *(ushort4*)(Upre + (((size_t)s * 32 + bt) * 16 + col) * 1024 + jv) = o;
      }
    }
  }
}

// ---------------------------------------------------------------------------
// recur: 32 persistent blocks x 512 thr (8 waves), 16 batch rows/block.
// R8 structure: Wz/Wr reg-resident, Whh in swizzled LDS, Ub prefetched
// across raw barriers, exp2-native activations, zero-VALU LDS addressing.
// ---------------------------------------------------------------------------
__global__ __launch_bounds__(512, 2) void recur(const unsigned short* __restrict__ Upre,
                                                const unsigned short* __restrict__ Wzrh,
                                                const unsigned short* __restrict__ WhhP,
                                                float* __restrict__ hT) {
  __shared__ unsigned short hb[16 * 256];   // decayed h bf16, 512B rows, swizzled
  __shared__ unsigned short qb[16 * 256];   // q = sig(r)*h bf16, swizzled
  __shared__ unsigned short WhL[65536];     // Whh, XOR-swizzled rows (131072 B)
  int bt = blockIdx.x, tid = threadIdx.x;
  int wid = tid >> 6, lane = tid & 63, col = lane & 15, kq = lane >> 4;
  const int hsw = (col & 7) << 4;

  // stage Whh -> LDS, swizzle byte ^= (row&7)<<4; 32 16B-chunks per 512B row.
#pragma unroll
  for (int i = 0; i < 16; ++i) {
    int f = tid + i * 512;
    int row = f >> 5, c = f & 31;
    bf16x8 v = *(const bf16x8*)(WhhP + (size_t)f * 8);
    *(bf16x8*)((char*)WhL + row * 512 + ((c * 16) ^ ((row & 7) << 4))) = v;
  }
  for (int i = tid; i < 16 * 256; i += 512) hb[i] = 0;

  // persistent z/r weight fragments (A-operand layout)
  bf16x8 wzf[2][8], wrf[2][8];
#pragma unroll
  for (int mt = 0; mt < 2; ++mt)
#pragma unroll
    for (int kt = 0; kt < 8; ++kt) {
      int j = wid * 32 + mt * 16 + col;
      wzf[mt][kt] = *(const bf16x8*)(Wzrh + (size_t)j * 256 + kt * 32 + kq * 8);
      wrf[mt][kt] = *(const bf16x8*)(Wzrh + (size_t)(256 + j) * 256 + kt * 32 + kq * 8);
      PINV(wzf[mt][kt]);
      PINV(wrf[mt][kt]);
    }

  const int joff0 = wid * 32 + kq * 4;
  // zero-VALU swizzled addressing (bit-6 / bits<6 exact split of the XOR)
  const int hs_lo = hsw & 48, hs_hi = hsw & 64;
  const int cq  = (kq * 16) ^ hs_lo;
  const int rbA = col * 512 + cq + hs_hi;           // even kt
  const int rbB = col * 512 + cq - hs_hi;           // odd kt
  const int row0 = wid * 32 + col;                  // (row0&7)==(col&7)
  const int wrbA = row0 * 512 + cq + hs_hi;
  const int wrbB = row0 * 512 + cq - hs_hi;
  const int wby0 = col * 512 + ((joff0 * 2) ^ hsw);        // write byte, mt=0
  const int wby1 = col * 512 + (((joff0 + 16) * 2) ^ hsw); // write byte, mt=1

  const unsigned short* Ub0 = Upre + ((size_t)bt * 16 + col) * 1024;
  const size_t SS = 32 * 16 * 1024;  // per-step stride (shorts)

  ushort4 uz[2], ur[2], uh[2], ug[2];
#pragma unroll
  for (int mt = 0; mt < 2; ++mt) {
    uz[mt] = *(const ushort4*)(Ub0 + 0   + joff0 + mt * 16);
    ur[mt] = *(const ushort4*)(Ub0 + 256 + joff0 + mt * 16);
    uh[mt] = *(const ushort4*)(Ub0 + 512 + joff0 + mt * 16);
    ug[mt] = *(const ushort4*)(Ub0 + SS + 768 + joff0 + mt * 16);  // DH, step 1
  }
  const unsigned short* pnext = Ub0 + SS + joff0;       // step s+1 base
  const unsigned short* pg    = Ub0 + 2 * SS + 768 + joff0;  // DH, step s+2
  f32x4 Hst[2] = {{0,0,0,0},{0,0,0,0}};
  float zk[2][4];
  BSYNC();

  for (int s = 0; s < NSTEP; ++s) {
    // ---- GEMM1: z and r (4 independent accumulation chains) ----
    f32x4 Cz[2] = {{0,0,0,0},{0,0,0,0}}, Cr[2] = {{0,0,0,0},{0,0,0,0}};
#pragma unroll
    for (int kt = 0; kt < 8; ++kt) {
      bf16x8 b = *(const bf16x8*)((const char*)hb + ((kt & 1) ? rbB : rbA) + kt * 64);
      Cz[0] = __builtin_amdgcn_mfma_f32_16x16x32_bf16(wzf[0][kt], b, Cz[0], 0, 0, 0);
      Cr[0] = __builtin_amdgcn_mfma_f32_16x16x32_bf16(wrf[0][kt], b, Cr[0], 0, 0, 0);
      Cz[1] = __builtin_amdgcn_mfma_f32_16x16x32_bf16(wzf[1][kt], b, Cz[1], 0, 0, 0);
      Cr[1] = __builtin_amdgcn_mfma_f32_16x16x32_bf16(wrf[1][kt], b, Cr[1], 0, 0, 0);
    }
    // epilogue: z kept in regs, q -> LDS via cvt_pk (exp2-native sigmoids)
#pragma unroll
    for (int mt = 0; mt < 2; ++mt) {
      float qv[4];
#pragma unroll
      for (int r = 0; r < 4; ++r) {
        float xz = Cz[mt][r] + bf2f(us4_get(uz[mt], r));
        float xr = Cr[mt][r] + bf2f(us4_get(ur[mt], r));
        float zv = __builtin_amdgcn_rcpf(1.f + __builtin_amdgcn_exp2f(-xz));
        float rv = __builtin_amdgcn_rcpf(1.f + __builtin_amdgcn_exp2f(-xr));
        zk[mt][r] = zv;
        qv[r] = rv * Hst[mt][r];
      }
      uint2 qw;
      qw.x = cvt_pk_bf16(qv[0], qv[1]);
      qw.y = cvt_pk_bf16(qv[2], qv[3]);
      *(uint2*)((char*)qb + (mt ? wby1 : wby0)) = qw;
    }
    // prefetch uz/ur for s+1 (in flight across the raw barrier)
#pragma unroll
    for (int mt = 0; mt < 2; ++mt) {
      uz[mt] = *(const ushort4*)(pnext + 0   + mt * 16);
      ur[mt] = *(const ushort4*)(pnext + 256 + mt * 16);
    }
    BSYNC();
    // ---- GEMM2: ht (Whh from swizzled LDS, imm-offset reads) ----
    f32x4 Ch[2] = {{0,0,0,0},{0,0,0,0}};
#pragma unroll
    for (int kt = 0; kt < 8; ++kt) {
      int ro = ((kt & 1) ? rbB : rbA) + kt * 64;
      int wo = ((kt & 1) ? wrbB : wrbA) + kt * 64;
      bf16x8 b  = *(const bf16x8*)((const char*)qb + ro);
      bf16x8 w0 = *(const bf16x8*)((const char*)WhL + wo);
      bf16x8 w1 = *(const bf16x8*)((const char*)WhL + wo + 16 * 512);
      Ch[0] = __builtin_amdgcn_mfma_f32_16x16x32_bf16(w0, b, Ch[0], 0, 0, 0);
      Ch[1] = __builtin_amdgcn_mfma_f32_16x16x32_bf16(w1, b, Ch[1], 0, 0, 0);
    }
    // epilogue: ht (exp2-native tanh), state update, decay via precomputed DH
#pragma unroll
    for (int mt = 0; mt < 2; ++mt) {
      float hn[4];
#pragma unroll
      for (int r = 0; r < 4; ++r) {
        float p = Ch[mt][r] + bf2f(us4_get(uh[mt], r));   // already 2log2e-scaled
        float e = __builtin_amdgcn_exp2f(p);
        float rr = __builtin_amdgcn_rcpf(e + 1.f);
        float th = fmaf(-2.f, rr, 1.f);
        float H = Hst[mt][r];
        hn[r] = fmaf(zk[mt][r], th - H, H);
      }
      if (s < NSTEP - 1) {
        float Hn[4];
#pragma unroll
        for (int r = 0; r < 4; ++r) {
          Hn[r] = hn[r] * bf2f(us4_get(ug[mt], r));  // ug holds DH already
          Hst[mt][r] = Hn[r];
        }
        uint2 hw;
        hw.x = cvt_pk_bf16(Hn[0], Hn[1]);
        hw.y = cvt_pk_bf16(Hn[2], Hn[3]);
        *(uint2*)((char*)hb + (mt ? wby1 : wby0)) = hw;
      } else {
        float4 o4; o4.x = hn[0]; o4.y = hn[1]; o4.z = hn[2]; o4.w = hn[3];
        *(float4*)&hT[((size_t)bt * 16 + col) * 256 + joff0 + mt * 16] = o4;
      }
    }
    // prefetch uh for s+1, DH for s+2 (overshoot in-bounds, unused)
#pragma unroll
    for (int mt = 0; mt < 2; ++mt) {
      uh[mt] = *(const ushort4*)(pnext + 512 + mt * 16);
      ug[mt] = *(const ushort4*)(pg + mt * 16);
    }
    pnext += SS;
    pg += SS;
    BSYNC();
  }
}

// ---------------------------------------------------------------------------
// bn_stats: one block per feature j; 64 lanes reduce over batch.
// av[j] = scale; av[256+j] = per-feature bias term (no atomics).
// ---------------------------------------------------------------------------
__global__ __launch_bounds__(64) void bn_stats(const float* __restrict__ hT,
                                               const float* __restrict__ gamma,
                                               const float* __restrict__ beta,
                                               const float* __restrict__ Wfc,
                                               const float* __restrict__ bfc,
                                               float* __restrict__ av) {
  int j = blockIdx.x, lane = threadIdx.x;
  float sum = 0.f, sum2 = 0.f;
#pragma unroll
  for (int b = lane; b < NBAT; b += 64) {
    float v = hT[(size_t)b * 256 + j];
    sum += v; sum2 += v * v;
  }
  for (int o = 32; o; o >>= 1) {
    sum  += __shfl_down(sum, o);
    sum2 += __shfl_down(sum2, o);
  }
  if (lane == 0) {
    float mu = sum * (1.f / NBAT);
    float var = sum2 * (1.f / NBAT) - mu * mu;
    float a = gamma[j] * Wfc[j] * rsqrtf(var + 1e-5f);
    av[j] = a;
    av[256 + j] = beta[j] * Wfc[j] - a * mu + (j == 0 ? bfc[0] : 0.f);
  }
}

__global__ __launch_bounds__(64) void fin(const float* __restrict__ hT,
                                          const float* __restrict__ av,
                                          float* __restrict__ out) {
  int b = blockIdx.x, lane = threadIdx.x;
  float4 hv = *(const float4*)&hT[(size_t)b * 256 + lane * 4];
  float4 a  = *(const float4*)&av[lane * 4];
  float4 c  = *(const float4*)&av[256 + lane * 4];
  float d = hv.x * a.x + hv.y * a.y + hv.z * a.z + hv.w * a.w
          + c.x + c.y + c.z + c.w;   // reduce sums all 256 bias terms once
  for (int o = 32; o; o >>= 1) d += __shfl_down(d, o);
  if (lane == 0) out[b] = d;
}

extern "C" void kernel_launch(void* const* d_in, const int* in_sizes, int n_in,
                              void* d_out, int out_size, void* d_ws, size_t ws_size,
                              hipStream_t stream) {
  (void)in_sizes; (void)n_in; (void)out_size; (void)ws_size;
  const float* X     = (const float*)d_in[0];
  const float* Xmean = (const float*)d_in[1];
  const float* Wz    = (const float*)d_in[2];
  const float* bz    = (const float*)d_in[3];
  const float* Wr    = (const float*)d_in[4];
  const float* br    = (const float*)d_in[5];
  const float* Wh    = (const float*)d_in[6];
  const float* bh    = (const float*)d_in[7];
  const float* Wgx   = (const float*)d_in[8];
  const float* bgx   = (const float*)d_in[9];
  const float* Wgh   = (const float*)d_in[10];
  const float* bgh   = (const float*)d_in[11];
  const float* gamma = (const float*)d_in[12];
  const float* beta  = (const float*)d_in[13];
  const float* Wfc   = (const float*)d_in[14];
  const float* bfc   = (const float*)d_in[15];
  float* out = (float*)d_out;
  char* ws = (char*)d_ws;

  unsigned short* Upre = (unsigned short*)(ws + 0ull);           // 134217728 B
  unsigned short* Cin  = (unsigned short*)(ws + 134217728ull);   // 50331648 B
  unsigned short* Wpre = (unsigned short*)(ws + 184549376ull);   // 786432 B
  unsigned short* Wzrh = (unsigned short*)(ws + 185335808ull);   // 262144 B
  unsigned short* WhhP = (unsigned short*)(ws + 185597952ull);   // 131072 B
  float*          Bpre = (float*)(ws + 185729024ull);            // 4096 B
  float*          hT   = (float*)(ws + 185733120ull);            // 524288 B
  float*          av   = (float*)(ws + 186257408ull);            // 2048 B (512 f)

  prep_pack<<<1024 + 4616, 128, 0, stream>>>(X, Xmean, Wgx, bgx,
                                             Wz, Wr, Wh, Wgh, bz, br, bh, bgh,
                                             Cin, Wpre, Wzrh, WhhP, Bpre);
  u_gemm<<<1024, 256, 0, stream>>>(Cin, Wpre, Bpre, Upre);
  recur<<<32, 512, 0, stream>>>(Upre, Wzrh, WhhP, hT);
  bn_stats<<<256, 64, 0, stream>>>(hT, gamma, beta, Wfc, bfc, av);
  fin<<<512, 64, 0, stream>>>(hT, av, out);
}